// Round 1
// baseline (115.780 us; speedup 1.0000x reference)
//
#include <hip/hip_runtime.h>
#include <stdint.h>

#define TSEQ 4096
#define DMODEL 1024
#define N3 3072
#define NHEADS 16
#define HDIM 64
#define WINDOW 256

typedef __attribute__((ext_vector_type(8))) short short8;
typedef __attribute__((ext_vector_type(4))) float f32x4;

__device__ __forceinline__ unsigned short f2bf(float f) {
  unsigned u = __builtin_bit_cast(unsigned, f);
  return (unsigned short)((u + 0x7fffu + ((u >> 16) & 1u)) >> 16);
}

__device__ __forceinline__ f32x4 mfma16(short8 a, short8 b, f32x4 c) {
  return __builtin_amdgcn_mfma_f32_16x16x32_bf16(a, b, c, 0, 0, 0);
}

// async global->LDS, 16B per lane; lds dest must be wave-uniform base (HW adds lane*16)
__device__ __forceinline__ void g2lds16(const void* g, void* l) {
  __builtin_amdgcn_global_load_lds(
      (const __attribute__((address_space(1))) void*)(uintptr_t)g,
      (__attribute__((address_space(3))) void*)(uintptr_t)l,
      16, 0, 0);
}

// ---------------- convert / transpose ----------------

__global__ __launch_bounds__(256) void cvt_f32_bf16_v4(const float* __restrict__ in,
                                                       unsigned short* __restrict__ out) {
  int i = (blockIdx.x * 256 + threadIdx.x) * 4;
  float4 v = *(const float4*)(in + i);
  unsigned short o0 = f2bf(v.x), o1 = f2bf(v.y), o2 = f2bf(v.z), o3 = f2bf(v.w);
  unsigned long long packed = (unsigned long long)o0 | ((unsigned long long)o1 << 16) |
                              ((unsigned long long)o2 << 32) | ((unsigned long long)o3 << 48);
  *(unsigned long long*)(out + i) = packed;
}

// in [R][C] f32 -> out [C][R] bf16
__global__ __launch_bounds__(256) void transpose_cvt(const float* __restrict__ in,
                                                     unsigned short* __restrict__ out,
                                                     int R, int C) {
  __shared__ float tile[32][33];
  int c0 = blockIdx.x * 32;
  int r0 = blockIdx.y * 32;
  int tx = threadIdx.x, ty = threadIdx.y;
#pragma unroll
  for (int i = 0; i < 32; i += 8)
    tile[ty + i][tx] = in[(size_t)(r0 + ty + i) * C + c0 + tx];
  __syncthreads();
#pragma unroll
  for (int i = 0; i < 32; i += 8)
    out[(size_t)(c0 + ty + i) * R + r0 + tx] = f2bf(tile[tx][ty + i]);
}

// ---------------- GEMM: C[M][N] = A[M][K=1024] * BT[N][K]^T + bias ----------------
// EPI=0: scatter to Q[h][t][d], K[h][t][d], VT[h][d][t] (bf16)
// EPI=1: f32 out [M][1024]

template <int EPI>
__global__ __launch_bounds__(256)
void gemm_bf16_128(const unsigned short* __restrict__ A,
                   const unsigned short* __restrict__ BT,
                   const float* __restrict__ bias,
                   unsigned short* __restrict__ oQ,
                   unsigned short* __restrict__ oK,
                   unsigned short* __restrict__ oVT,
                   float* __restrict__ oF) {
  __shared__ unsigned short Asm[128 * 32];
  __shared__ unsigned short Bsm[128 * 32];
  const int K = 1024;
  int m0 = blockIdx.x * 128;
  int n0 = blockIdx.y * 128;
  int tid = threadIdx.x;
  int w = tid >> 6, lane = tid & 63;
  int l15 = lane & 15, l4 = lane >> 4;
  int wm = (w >> 1) * 64, wn = (w & 1) * 64;

  f32x4 acc[4][4];
#pragma unroll
  for (int i = 0; i < 4; i++)
#pragma unroll
    for (int j = 0; j < 4; j++) acc[i][j] = (f32x4){0.f, 0.f, 0.f, 0.f};

  // staging: chunk c = w*2+r covers rows c*16..c*16+15 (1KB each), lane -> (row c*16+lane/4, k (lane&3)*8)
  const unsigned short* aSrc = A + (size_t)(m0 + w * 32 + (lane >> 2)) * K + (lane & 3) * 8;
  const unsigned short* bSrc = BT + (size_t)(n0 + w * 32 + (lane >> 2)) * K + (lane & 3) * 8;
  unsigned short* aDst0 = &Asm[(w * 2 + 0) * 512];
  unsigned short* aDst1 = &Asm[(w * 2 + 1) * 512];
  unsigned short* bDst0 = &Bsm[(w * 2 + 0) * 512];
  unsigned short* bDst1 = &Bsm[(w * 2 + 1) * 512];

  for (int k0 = 0; k0 < K; k0 += 32) {
    g2lds16(aSrc + k0, aDst0);
    g2lds16(aSrc + 16 * K + k0, aDst1);
    g2lds16(bSrc + k0, bDst0);
    g2lds16(bSrc + 16 * K + k0, bDst1);
    __syncthreads();
    short8 af[4], bfr[4];
#pragma unroll
    for (int mi = 0; mi < 4; mi++)
      af[mi] = *(const short8*)&Asm[(wm + mi * 16 + l15) * 32 + l4 * 8];
#pragma unroll
    for (int ni = 0; ni < 4; ni++)
      bfr[ni] = *(const short8*)&Bsm[(wn + ni * 16 + l15) * 32 + l4 * 8];
#pragma unroll
    for (int mi = 0; mi < 4; mi++)
#pragma unroll
      for (int ni = 0; ni < 4; ni++)
        acc[mi][ni] = mfma16(af[mi], bfr[ni], acc[mi][ni]);
    __syncthreads();
  }

#pragma unroll
  for (int ni = 0; ni < 4; ni++) {
    int nn = n0 + wn + ni * 16 + l15;
    float bv = bias[nn];
#pragma unroll
    for (int mi = 0; mi < 4; mi++) {
#pragma unroll
      for (int r = 0; r < 4; r++) {
        int mm = m0 + wm + mi * 16 + l4 * 4 + r;
        float v = acc[mi][ni][r] + bv;
        if (EPI == 0) {
          unsigned short hv = f2bf(v);
          int c = nn & 1023;
          int hh = c >> 6, dd = c & 63;
          if (nn < 1024)
            oQ[((size_t)hh * TSEQ + mm) * 64 + dd] = hv;
          else if (nn < 2048)
            oK[((size_t)hh * TSEQ + mm) * 64 + dd] = hv;
          else
            oVT[((size_t)hh * 64 + dd) * TSEQ + mm] = hv;
        } else {
          oF[(size_t)mm * 1024 + nn] = v;
        }
      }
    }
  }
}

// ---------------- sliding-window attention ----------------
// grid (TSEQ/64, NHEADS), 4 waves; wave w owns q rows qb*64+w*16 .. +15

__global__ __launch_bounds__(256)
void attn_swa(const unsigned short* __restrict__ Q,
              const unsigned short* __restrict__ Kk,
              const unsigned short* __restrict__ Vt,
              unsigned short* __restrict__ Y) {
  __shared__ unsigned char Pl[4][2048];
  int qb = blockIdx.x;
  int h = blockIdx.y;
  int w = threadIdx.x >> 6, lane = threadIdx.x & 63;
  int l15 = lane & 15, l4 = lane >> 4;
  int qrow0 = qb * 64 + w * 16;

  const unsigned short* qp = Q + ((size_t)(h * TSEQ + qrow0 + l15)) * 64 + l4 * 8;
  short8 qa0 = *(const short8*)qp;
  short8 qa1 = *(const short8*)(qp + 32);

  float mrow[4], lrow[4];
  f32x4 o[4];
#pragma unroll
  for (int r = 0; r < 4; r++) { mrow[r] = -1e30f; lrow[r] = 0.f; }
#pragma unroll
  for (int ni = 0; ni < 4; ni++) o[ni] = (f32x4){0.f, 0.f, 0.f, 0.f};

  unsigned char* pw = Pl[w];
  int kt0 = qb >= 4 ? qb - 4 : 0;
  for (int kt = kt0; kt <= qb; ++kt) {
    int kbase = kt * 64;
    const unsigned short* kp = Kk + ((size_t)(h * TSEQ + kbase)) * 64;
    f32x4 s[4];
#pragma unroll
    for (int ni = 0; ni < 4; ni++) {
      const unsigned short* kr = kp + (ni * 16 + l15) * 64 + l4 * 8;
      short8 b0 = *(const short8*)kr;
      short8 b1 = *(const short8*)(kr + 32);
      f32x4 z = (f32x4){0.f, 0.f, 0.f, 0.f};
      z = mfma16(qa0, b0, z);
      s[ni] = mfma16(qa1, b1, z);
    }
    // scale + window mask (sentinel -1e30 keeps fully-masked rows finite)
#pragma unroll
    for (int ni = 0; ni < 4; ni++) {
      int kk = kbase + ni * 16 + l15;
#pragma unroll
      for (int r = 0; r < 4; r++) {
        int diff = (qrow0 + l4 * 4 + r) - kk;
        float v = s[ni][r] * 0.125f;
        s[ni][r] = (diff >= 0 && diff < WINDOW) ? v : -1e30f;
      }
    }
    float alpha[4];
#pragma unroll
    for (int r = 0; r < 4; r++) {
      float pm = fmaxf(fmaxf(s[0][r], s[1][r]), fmaxf(s[2][r], s[3][r]));
      pm = fmaxf(pm, __shfl_xor(pm, 1, 64));
      pm = fmaxf(pm, __shfl_xor(pm, 2, 64));
      pm = fmaxf(pm, __shfl_xor(pm, 4, 64));
      pm = fmaxf(pm, __shfl_xor(pm, 8, 64));
      float mn = fmaxf(mrow[r], pm);
      alpha[r] = __expf(mrow[r] - mn);
      mrow[r] = mn;
    }
    float rs[4] = {0.f, 0.f, 0.f, 0.f};
#pragma unroll
    for (int ni = 0; ni < 4; ni++)
#pragma unroll
      for (int r = 0; r < 4; r++) {
        float p = __expf(s[ni][r] - mrow[r]);
        s[ni][r] = p;
        rs[r] += p;
      }
#pragma unroll
    for (int r = 0; r < 4; r++) {
      float t = rs[r];
      t += __shfl_xor(t, 1, 64);
      t += __shfl_xor(t, 2, 64);
      t += __shfl_xor(t, 4, 64);
      t += __shfl_xor(t, 8, 64);
      lrow[r] = lrow[r] * alpha[r] + t;
    }
    // P (C-layout) -> LDS bf16, XOR-swizzled rows to kill the 128B-stride bank conflict
#pragma unroll
    for (int ni = 0; ni < 4; ni++)
#pragma unroll
      for (int r = 0; r < 4; r++) {
        int row = l4 * 4 + r;
        int cb = (ni * 16 + l15) * 2;
        *(unsigned short*)(pw + row * 128 + (cb ^ ((row & 7) << 4))) = f2bf(s[ni][r]);
      }
    short8 pa0, pa1;
    {
      int row = l15;
      int sw = (row & 7) << 4;
      pa0 = *(const short8*)(pw + row * 128 + ((l4 * 16) ^ sw));
      pa1 = *(const short8*)(pw + row * 128 + ((64 + l4 * 16) ^ sw));
    }
#pragma unroll
    for (int ni = 0; ni < 4; ni++)
#pragma unroll
      for (int r = 0; r < 4; r++) o[ni][r] *= alpha[r];
    const unsigned short* vp = Vt + (size_t)h * 64 * TSEQ + kbase;
#pragma unroll
    for (int ni = 0; ni < 4; ni++) {
      const unsigned short* vr = vp + (size_t)(ni * 16 + l15) * TSEQ + l4 * 8;
      short8 v0 = *(const short8*)vr;
      short8 v1 = *(const short8*)(vr + 32);
      o[ni] = mfma16(pa0, v0, o[ni]);
      o[ni] = mfma16(pa1, v1, o[ni]);
    }
  }
#pragma unroll
  for (int ni = 0; ni < 4; ni++) {
    int dd = ni * 16 + l15;
#pragma unroll
    for (int r = 0; r < 4; r++) {
      int qq = qrow0 + l4 * 4 + r;
      Y[(size_t)qq * DMODEL + h * 64 + dd] = f2bf(o[ni][r] / lrow[r]);
    }
  }
}

// ---------------- launch ----------------

extern "C" void kernel_launch(void* const* d_in, const int* in_sizes, int n_in,
                              void* d_out, int out_size, void* d_ws, size_t ws_size,
                              hipStream_t stream) {
  const float* x = (const float*)d_in[0];
  const float* Wqkv = (const float*)d_in[1];
  const float* bqkv = (const float*)d_in[2];
  const float* Wproj = (const float*)d_in[3];
  const float* bproj = (const float*)d_in[4];
  float* out = (float*)d_out;

  unsigned short* ws = (unsigned short*)d_ws;
  unsigned short* xb = ws;                                        // [4096][1024]
  unsigned short* wqkvT = xb + (size_t)TSEQ * DMODEL;             // [3072][1024]
  unsigned short* wprojT = wqkvT + (size_t)N3 * DMODEL;           // [1024][1024]
  unsigned short* qarr = wprojT + (size_t)DMODEL * DMODEL;        // [16][4096][64]
  unsigned short* karr = qarr + (size_t)NHEADS * TSEQ * HDIM;     // [16][4096][64]
  unsigned short* vtarr = karr + (size_t)NHEADS * TSEQ * HDIM;    // [16][64][4096]
  unsigned short* yarr = vtarr + (size_t)NHEADS * TSEQ * HDIM;    // [4096][1024]

  cvt_f32_bf16_v4<<<(TSEQ * DMODEL) / 1024, 256, 0, stream>>>(x, xb);
  transpose_cvt<<<dim3(N3 / 32, DMODEL / 32), dim3(32, 8), 0, stream>>>(Wqkv, wqkvT, DMODEL, N3);
  transpose_cvt<<<dim3(DMODEL / 32, DMODEL / 32), dim3(32, 8), 0, stream>>>(Wproj, wprojT, DMODEL, DMODEL);
  gemm_bf16_128<0><<<dim3(TSEQ / 128, N3 / 128), 256, 0, stream>>>(xb, wqkvT, bqkv, qarr, karr, vtarr, nullptr);
  attn_swa<<<dim3(TSEQ / 64, NHEADS), 256, 0, stream>>>(qarr, karr, vtarr, yarr);
  gemm_bf16_128<1><<<dim3(TSEQ / 128, DMODEL / 128), 256, 0, stream>>>(yarr, wprojT, bproj, nullptr, nullptr, nullptr, out);
}